// Round 5
// baseline (323.251 us; speedup 1.0000x reference)
//
#include <hip/hip_runtime.h>

#define TSTEPS 8192
#define HDIM 4096
#define PDIM 4
#define KDIM 64

typedef unsigned short u16;
typedef __attribute__((ext_vector_type(8))) short short8;
typedef __attribute__((ext_vector_type(4))) float f32x4;

#define S1 -1.44269504089f   // -log2(e)
#define S2 -2.88539008177f   // -2*log2(e)

#if __has_builtin(__builtin_amdgcn_exp2f)
#define EXP2(x) __builtin_amdgcn_exp2f(x)
#else
#define EXP2(x) exp2f(x)
#endif
__device__ __forceinline__ float rcpf(float x) { return __builtin_amdgcn_rcpf(x); }

__device__ __forceinline__ u16 bf16_rne(float f) {
  unsigned u = __float_as_uint(f);
  u += 0x7FFF + ((u >> 16) & 1);
  return (u16)(u >> 16);
}
__device__ __forceinline__ void hilo(float v, u16& h, u16& l) {
  h = bf16_rne(v);
  l = bf16_rne(v - __uint_as_float((unsigned)h << 16));
}

// ---- workspace layout (float offsets) ----
#define WS_Y0   0
#define WS_Y1   32768
#define WS_BSC  65536
#define WS_C1   77824
#define WS_C2   159744
#define WS_XHI  241664
#define WS_XLO  503808
#define WS_WHI  765952
#define WS_WLO  1159168

// One-shot prep: bf16 hi/lo conversion of x and W_ih0 (i,g,o rows, PRE-SCALED
// by S1/S2 so gate accumulators feed v_exp directly), scaled merged biases,
// packed per-j constant records for layers 1/2, and zeroing of y0/y1/out.
__global__ void prep_kernel(const float* __restrict__ x,
                            const float* __restrict__ Wih0, const float* __restrict__ bih0,
                            const float* __restrict__ bhh0,
                            const float* __restrict__ Wih1, const float* __restrict__ bih1,
                            const float* __restrict__ bhh1, const float* __restrict__ Whr1,
                            const float* __restrict__ Wih2, const float* __restrict__ bih2,
                            const float* __restrict__ bhh2, const float* __restrict__ Whr2,
                            float* __restrict__ ws, float* __restrict__ out) {
  const int i = blockIdx.x * 256 + threadIdx.x;
  u16* xhi = (u16*)(ws + WS_XHI);
  u16* xlo = (u16*)(ws + WS_XLO);
  u16* whi = (u16*)(ws + WS_WHI);
  u16* wlo = (u16*)(ws + WS_WLO);

  if (i < 131072) {                       // x: 131072 float4 units, unscaled
    float4 v = *(const float4*)&x[i * 4];
    float val[4] = {v.x, v.y, v.z, v.w};
    u16 h[4], l[4];
#pragma unroll
    for (int e = 0; e < 4; ++e) hilo(val[e], h[e], l[e]);
    *(ushort4*)&xhi[i * 4] = make_ushort4(h[0], h[1], h[2], h[3]);
    *(ushort4*)&xlo[i * 4] = make_ushort4(l[0], l[1], l[2], l[3]);
  } else if (i < 327680) {                // W_ih0: 196608 float4 units, scaled
    int f = i - 131072;
    int el4 = f * 4;
    int r = el4 >> 6;                     // packed row 0..12287 ([gate][j])
    int k4 = el4 & 63;
    int gate = r >> 12, jr = r & 4095;
    int src = (gate == 0) ? jr : (gate + 1) * HDIM + jr;   // i,g,o = rows 0,2H,3H
    float sc = (gate == 1) ? S2 : S1;
    float4 v = *(const float4*)&Wih0[(size_t)src * KDIM + k4];
    float val[4] = {sc * v.x, sc * v.y, sc * v.z, sc * v.w};
    u16 h[4], l[4];
#pragma unroll
    for (int e = 0; e < 4; ++e) hilo(val[e], h[e], l[e]);
    *(ushort4*)&whi[r * KDIM + k4] = make_ushort4(h[0], h[1], h[2], h[3]);
    *(ushort4*)&wlo[r * KDIM + k4] = make_ushort4(l[0], l[1], l[2], l[3]);
  } else if (i < 339968) {                // bsc[3][4096], scaled merged bias
    int f = i - 327680;
    int g = f >> 12, j = f & 4095;
    int src = (g == 0) ? j : (g + 1) * HDIM + j;
    float sc = (g == 1) ? S2 : S1;
    ws[WS_BSC + f] = sc * (bih0[src] + bhh0[src]);
  } else if (i < 348160) {                // c1/c2 packed records (20 floats/j)
    int f = i - 339968;
    const float* Wih = (f < 4096) ? Wih1 : Wih2;
    const float* bih = (f < 4096) ? bih1 : bih2;
    const float* bhh = (f < 4096) ? bhh1 : bhh2;
    const float* Whr = (f < 4096) ? Whr1 : Whr2;
    float* c = ws + ((f < 4096) ? WS_C1 : WS_C2);
    int j = f & 4095;
    float4 wi = *(const float4*)&Wih[(size_t)j * 4];
    float4 wg = *(const float4*)&Wih[(size_t)(2 * HDIM + j) * 4];
    float4 wo = *(const float4*)&Wih[(size_t)(3 * HDIM + j) * 4];
    float* cb = c + j * 20;
    *(float4*)(cb + 0)  = make_float4(S1 * wi.x, S1 * wi.y, S1 * wi.z, S1 * wi.w);
    *(float4*)(cb + 4)  = make_float4(S2 * wg.x, S2 * wg.y, S2 * wg.z, S2 * wg.w);
    *(float4*)(cb + 8)  = make_float4(S1 * wo.x, S1 * wo.y, S1 * wo.z, S1 * wo.w);
    *(float4*)(cb + 12) = make_float4(S1 * (bih[j] + bhh[j]),
                                      S2 * (bih[2 * HDIM + j] + bhh[2 * HDIM + j]),
                                      S1 * (bih[3 * HDIM + j] + bhh[3 * HDIM + j]), 0.f);
    *(float4*)(cb + 16) = make_float4(Whr[j], Whr[HDIM + j], Whr[2 * HDIM + j], Whr[3 * HDIM + j]);
  } else if (i < 446464) {                // zero y0,y1,out
    int f = i - 348160;
    if (f < 65536) ws[f] = 0.0f;
    else out[f - 65536] = 0.0f;
  }
}

// Layer 0: MFMA 16x16x32 bf16 on pre-converted, pre-scaled hi/lo fragments.
// Wave tile 32t x 32j x 3 gates (js=2 -> 48 AGPR): total regs < 128 ->
// 4 waves/SIMD (2x round-4 occupancy; kernel was 70% latency-idle).
// Block = 4 waves = 128t x 32j; grid = 64 t-blocks x 128 j-blocks = 8192.
__global__ __launch_bounds__(256, 4)
void lstm_layer0_mfma(const u16* __restrict__ xhi, const u16* __restrict__ xlo,
                      const u16* __restrict__ whi, const u16* __restrict__ wlo,
                      const float* __restrict__ bsc, const float* __restrict__ Whr,
                      float* __restrict__ yout) {
  __shared__ float hsh[128 * 33];           // 16.5 KB
  const int tid = threadIdx.x;
  const int w = tid >> 6;
  const int lane = tid & 63;
  const int m = lane & 15;
  const int q = lane >> 4;
  const int jb = blockIdx.x & 127;
  const int tb = blockIdx.x >> 7;
  const int j0 = jb * 32;
  const int t0 = tb * 128 + w * 32;

  f32x4 acc[2][2][3];
#pragma unroll
  for (int ts = 0; ts < 2; ++ts)
#pragma unroll
    for (int js = 0; js < 2; ++js)
#pragma unroll
      for (int g = 0; g < 3; ++g) acc[ts][js][g] = (f32x4){0.f, 0.f, 0.f, 0.f};

#pragma unroll
  for (int kc = 0; kc < 2; ++kc) {
    const int k0 = kc * 32 + q * 8;
    short8 ah[2], al[2];
#pragma unroll
    for (int ts = 0; ts < 2; ++ts) {
      size_t ax = (size_t)(t0 + ts * 16 + m) * KDIM + k0;
      ah[ts] = *(const short8*)&xhi[ax];
      al[ts] = *(const short8*)&xlo[ax];
    }
#pragma unroll
    for (int js = 0; js < 2; ++js) {
      const int j = j0 + js * 16 + m;
#pragma unroll
      for (int g = 0; g < 3; ++g) {
        size_t bx = (size_t)(g * HDIM + j) * KDIM + k0;
        short8 bh = *(const short8*)&whi[bx];
        short8 bl = *(const short8*)&wlo[bx];
#pragma unroll
        for (int ts = 0; ts < 2; ++ts) {
          acc[ts][js][g] = __builtin_amdgcn_mfma_f32_16x16x32_bf16(ah[ts], bh, acc[ts][js][g], 0, 0, 0);
          acc[ts][js][g] = __builtin_amdgcn_mfma_f32_16x16x32_bf16(ah[ts], bl, acc[ts][js][g], 0, 0, 0);
          acc[ts][js][g] = __builtin_amdgcn_mfma_f32_16x16x32_bf16(al[ts], bh, acc[ts][js][g], 0, 0, 0);
        }
      }
    }
  }

  // epilogue: gates already exp2-args; h -> LDS (stride 33, <=2-way = free)
#pragma unroll
  for (int js = 0; js < 2; ++js) {
    const int j = j0 + js * 16 + m;
    float bi = bsc[j];
    float bg = bsc[HDIM + j];
    float bo = bsc[2 * HDIM + j];
#pragma unroll
    for (int ts = 0; ts < 2; ++ts) {
#pragma unroll
      for (int r = 0; r < 4; ++r) {
        float ea = EXP2(acc[ts][js][0][r] + bi);          // e^-i
        float eb = EXP2(acc[ts][js][1][r] + bg);          // e^-2g
        float c = (1.0f - eb) * rcpf((1.0f + ea) * (1.0f + eb));   // sig(i)tanh(g)
        float ec = EXP2(acc[ts][js][2][r] + bo);          // e^-o
        float ed = EXP2(S2 * c);                          // e^-2c
        float h = (1.0f - ed) * rcpf((1.0f + ec) * (1.0f + ed));   // sig(o)tanh(c)
        int tl = w * 32 + ts * 16 + q * 4 + r;
        hsh[tl * 33 + js * 16 + m] = h;
      }
    }
  }
  __syncthreads();

  // fused projection over this block's 32 j; 2 atomics/thread
  const int tl = tid & 127;
  const int p0 = (tid >> 7) * 2;
  float s0 = 0.f, s1 = 0.f;
#pragma unroll
  for (int cch = 0; cch < 4; ++cch) {
    const float* wp0 = Whr + (size_t)p0 * HDIM + j0 + cch * 8;
    const float* wp1 = Whr + (size_t)(p0 + 1) * HDIM + j0 + cch * 8;
    float4 w0a = *(const float4*)wp0, w0b = *(const float4*)(wp0 + 4);
    float4 w1a = *(const float4*)wp1, w1b = *(const float4*)(wp1 + 4);
    float wa[8] = {w0a.x, w0a.y, w0a.z, w0a.w, w0b.x, w0b.y, w0b.z, w0b.w};
    float wb[8] = {w1a.x, w1a.y, w1a.z, w1a.w, w1b.x, w1b.y, w1b.z, w1b.w};
#pragma unroll
    for (int e = 0; e < 8; ++e) {
      float h = hsh[tl * 33 + cch * 8 + e];
      s0 = fmaf(h, wa[e], s0);
      s1 = fmaf(h, wb[e], s1);
    }
  }
  const int tg = tb * 128 + tl;
  atomicAdd(&yout[(size_t)tg * PDIM + p0], s0);
  atomicAdd(&yout[(size_t)tg * PDIM + p0 + 1], s1);
}

// Layers 1-2 (K=4): lane = timestep, wave-uniform j loop over packed 20-float
// pre-scaled records. JPB=64 -> grid 2048 -> 8 blocks/CU; bounds (256,8) for
// 8 waves/SIMD (VALU floor ~21 us/layer; extra waves hide s_load latency).
__global__ __launch_bounds__(256, 8)
void lstm_small(const float* __restrict__ xin, const float* __restrict__ cpk,
                float* __restrict__ yout) {
  constexpr int JPB = 64, JSPLIT = HDIM / JPB;   // 64
  const int tid = threadIdx.x;
  const int t = (blockIdx.x >> 6) * 256 + tid;
  const int j0 = (blockIdx.x & 63) * JPB;

  float4 xv = *(const float4*)&xin[(size_t)t * 4];
  float o0 = 0.f, o1 = 0.f, o2 = 0.f, o3 = 0.f;

#pragma unroll 4
  for (int jj = 0; jj < JPB; ++jj) {
    const float* cb = cpk + (size_t)(j0 + jj) * 20;
    float4 wi = *(const float4*)(cb + 0);
    float4 wg = *(const float4*)(cb + 4);
    float4 wo = *(const float4*)(cb + 8);
    float4 bb = *(const float4*)(cb + 12);
    float4 wr = *(const float4*)(cb + 16);
    float gi = bb.x, gg = bb.y, go = bb.z;
    gi = fmaf(xv.x, wi.x, gi); gi = fmaf(xv.y, wi.y, gi);
    gi = fmaf(xv.z, wi.z, gi); gi = fmaf(xv.w, wi.w, gi);
    gg = fmaf(xv.x, wg.x, gg); gg = fmaf(xv.y, wg.y, gg);
    gg = fmaf(xv.z, wg.z, gg); gg = fmaf(xv.w, wg.w, gg);
    go = fmaf(xv.x, wo.x, go); go = fmaf(xv.y, wo.y, go);
    go = fmaf(xv.z, wo.z, go); go = fmaf(xv.w, wo.w, go);
    float ea = EXP2(gi);
    float eb = EXP2(gg);
    float c = (1.0f - eb) * rcpf((1.0f + ea) * (1.0f + eb));
    float ec = EXP2(go);
    float ed = EXP2(S2 * c);
    float h = (1.0f - ed) * rcpf((1.0f + ec) * (1.0f + ed));
    o0 = fmaf(h, wr.x, o0);
    o1 = fmaf(h, wr.y, o1);
    o2 = fmaf(h, wr.z, o2);
    o3 = fmaf(h, wr.w, o3);
  }

  float* yt = yout + (size_t)t * PDIM;
  atomicAdd(&yt[0], o0);
  atomicAdd(&yt[1], o1);
  atomicAdd(&yt[2], o2);
  atomicAdd(&yt[3], o3);
}

extern "C" void kernel_launch(void* const* d_in, const int* in_sizes, int n_in,
                              void* d_out, int out_size, void* d_ws, size_t ws_size,
                              hipStream_t stream) {
  const float* x    = (const float*)d_in[0];
  const float* Wih0 = (const float*)d_in[1];
  const float* bih0 = (const float*)d_in[3];
  const float* bhh0 = (const float*)d_in[4];
  const float* Whr0 = (const float*)d_in[5];
  const float* Wih1 = (const float*)d_in[6];
  const float* bih1 = (const float*)d_in[8];
  const float* bhh1 = (const float*)d_in[9];
  const float* Whr1 = (const float*)d_in[10];
  const float* Wih2 = (const float*)d_in[11];
  const float* bih2 = (const float*)d_in[13];
  const float* bhh2 = (const float*)d_in[14];
  const float* Whr2 = (const float*)d_in[15];
  float* out = (float*)d_out;
  float* ws = (float*)d_ws;

  prep_kernel<<<dim3(1744), dim3(256), 0, stream>>>(
      x, Wih0, bih0, bhh0, Wih1, bih1, bhh1, Whr1, Wih2, bih2, bhh2, Whr2, ws, out);

  // layer 0: 64 t-blocks x 128 j-blocks
  lstm_layer0_mfma<<<dim3(8192), dim3(256), 0, stream>>>(
      (const u16*)(ws + WS_XHI), (const u16*)(ws + WS_XLO),
      (const u16*)(ws + WS_WHI), (const u16*)(ws + WS_WLO),
      ws + WS_BSC, Whr0, ws + WS_Y0);

  lstm_small<<<dim3(2048), dim3(256), 0, stream>>>(ws + WS_Y0, ws + WS_C1, ws + WS_Y1);
  lstm_small<<<dim3(2048), dim3(256), 0, stream>>>(ws + WS_Y1, ws + WS_C2, out);
}

// Round 6
// 299.284 us; speedup vs baseline: 1.0801x; 1.0801x over previous
//
#include <hip/hip_runtime.h>

#define TSTEPS 8192
#define HDIM 4096
#define PDIM 4
#define KDIM 64

typedef unsigned short u16;
typedef __attribute__((ext_vector_type(8))) short short8;
typedef __attribute__((ext_vector_type(4))) float f32x4;

#define S1 -1.44269504089f   // -log2(e)
#define S2 -2.88539008177f   // -2*log2(e)

#if __has_builtin(__builtin_amdgcn_exp2f)
#define EXP2(x) __builtin_amdgcn_exp2f(x)
#else
#define EXP2(x) exp2f(x)
#endif
__device__ __forceinline__ float rcpf(float x) { return __builtin_amdgcn_rcpf(x); }

__device__ __forceinline__ u16 bf16_rne(float f) {
  unsigned u = __float_as_uint(f);
  u += 0x7FFF + ((u >> 16) & 1);
  return (u16)(u >> 16);
}
__device__ __forceinline__ void hilo(float v, u16& h, u16& l) {
  h = bf16_rne(v);
  l = bf16_rne(v - __uint_as_float((unsigned)h << 16));
}

// ---- workspace layout (float offsets) ----
// y0, y1: reduced layer outputs [8192][4]
// pp: partial buffer [64 slices][8192 t][4 p] = 2M floats (reused by all layers)
#define WS_Y0   0
#define WS_Y1   32768
#define WS_BSC  65536
#define WS_C1   77824
#define WS_C2   159744
#define WS_XHI  241664
#define WS_XLO  503808
#define WS_WHI  765952
#define WS_WLO  1159168
#define WS_PP   1552384
// total 3649536 floats = 14.6 MB

// One-shot prep: bf16 hi/lo of x and W_ih0 (i,g,o rows, PRE-SCALED by S1/S2 so
// gates feed v_exp directly), scaled merged biases, packed per-j records for
// layers 1/2. No zeroing needed anywhere (no atomics downstream).
__global__ void prep_kernel(const float* __restrict__ x,
                            const float* __restrict__ Wih0, const float* __restrict__ bih0,
                            const float* __restrict__ bhh0,
                            const float* __restrict__ Wih1, const float* __restrict__ bih1,
                            const float* __restrict__ bhh1, const float* __restrict__ Whr1,
                            const float* __restrict__ Wih2, const float* __restrict__ bih2,
                            const float* __restrict__ bhh2, const float* __restrict__ Whr2,
                            float* __restrict__ ws) {
  const int i = blockIdx.x * 256 + threadIdx.x;
  u16* xhi = (u16*)(ws + WS_XHI);
  u16* xlo = (u16*)(ws + WS_XLO);
  u16* whi = (u16*)(ws + WS_WHI);
  u16* wlo = (u16*)(ws + WS_WLO);

  if (i < 131072) {                       // x: 131072 float4 units, unscaled
    float4 v = *(const float4*)&x[i * 4];
    float val[4] = {v.x, v.y, v.z, v.w};
    u16 h[4], l[4];
#pragma unroll
    for (int e = 0; e < 4; ++e) hilo(val[e], h[e], l[e]);
    *(ushort4*)&xhi[i * 4] = make_ushort4(h[0], h[1], h[2], h[3]);
    *(ushort4*)&xlo[i * 4] = make_ushort4(l[0], l[1], l[2], l[3]);
  } else if (i < 327680) {                // W_ih0: 196608 float4 units, scaled
    int f = i - 131072;
    int el4 = f * 4;
    int r = el4 >> 6;                     // packed row 0..12287 ([gate][j])
    int k4 = el4 & 63;
    int gate = r >> 12, jr = r & 4095;
    int src = (gate == 0) ? jr : (gate + 1) * HDIM + jr;   // i,g,o = rows 0,2H,3H
    float sc = (gate == 1) ? S2 : S1;
    float4 v = *(const float4*)&Wih0[(size_t)src * KDIM + k4];
    float val[4] = {sc * v.x, sc * v.y, sc * v.z, sc * v.w};
    u16 h[4], l[4];
#pragma unroll
    for (int e = 0; e < 4; ++e) hilo(val[e], h[e], l[e]);
    *(ushort4*)&whi[r * KDIM + k4] = make_ushort4(h[0], h[1], h[2], h[3]);
    *(ushort4*)&wlo[r * KDIM + k4] = make_ushort4(l[0], l[1], l[2], l[3]);
  } else if (i < 339968) {                // bsc[3][4096], scaled merged bias
    int f = i - 327680;
    int g = f >> 12, j = f & 4095;
    int src = (g == 0) ? j : (g + 1) * HDIM + j;
    float sc = (g == 1) ? S2 : S1;
    ws[WS_BSC + f] = sc * (bih0[src] + bhh0[src]);
  } else if (i < 348160) {                // c1/c2 packed records (20 floats/j)
    int f = i - 339968;
    const float* Wih = (f < 4096) ? Wih1 : Wih2;
    const float* bih = (f < 4096) ? bih1 : bih2;
    const float* bhh = (f < 4096) ? bhh1 : bhh2;
    const float* Whr = (f < 4096) ? Whr1 : Whr2;
    float* c = ws + ((f < 4096) ? WS_C1 : WS_C2);
    int j = f & 4095;
    float4 wi = *(const float4*)&Wih[(size_t)j * 4];
    float4 wg = *(const float4*)&Wih[(size_t)(2 * HDIM + j) * 4];
    float4 wo = *(const float4*)&Wih[(size_t)(3 * HDIM + j) * 4];
    float* cb = c + j * 20;
    *(float4*)(cb + 0)  = make_float4(S1 * wi.x, S1 * wi.y, S1 * wi.z, S1 * wi.w);
    *(float4*)(cb + 4)  = make_float4(S2 * wg.x, S2 * wg.y, S2 * wg.z, S2 * wg.w);
    *(float4*)(cb + 8)  = make_float4(S1 * wo.x, S1 * wo.y, S1 * wo.z, S1 * wo.w);
    *(float4*)(cb + 12) = make_float4(S1 * (bih[j] + bhh[j]),
                                      S2 * (bih[2 * HDIM + j] + bhh[2 * HDIM + j]),
                                      S1 * (bih[3 * HDIM + j] + bhh[3 * HDIM + j]), 0.f);
    *(float4*)(cb + 16) = make_float4(Whr[j], Whr[HDIM + j], Whr[2 * HDIM + j], Whr[3 * HDIM + j]);
  }
}

// Layer 0: MFMA 16x16x32 bf16, hi/lo 3-pass, big r4 tile (wave = 32t x 64j x
// 3 gates, 144 MFMA) restructured kc-OUTER so registers fit 3 waves/SIMD
// (acc 96 AGPR + x 16 + W window 24 + temps ~ 155 < 170), with depth-2
// register prefetch on W fragments. Block = 4 waves = 128t x 64j; grid 4096.
// NO atomics: block-reduced projection partials stored plain to pp[jb][t][4].
__global__ __launch_bounds__(256, 3)
void lstm_layer0_mfma(const u16* __restrict__ xhi, const u16* __restrict__ xlo,
                      const u16* __restrict__ whi, const u16* __restrict__ wlo,
                      const float* __restrict__ bsc, const float* __restrict__ Whr,
                      float* __restrict__ pp) {
  __shared__ float hsh[128 * 65];           // 33.3 KB
  const int tid = threadIdx.x;
  const int w = tid >> 6;
  const int lane = tid & 63;
  const int m = lane & 15;
  const int q = lane >> 4;
  const int jb = blockIdx.x & 63;
  const int tb = blockIdx.x >> 6;
  const int j0 = jb * 64;
  const int t0 = tb * 128 + w * 32;

  f32x4 acc[2][4][3];
#pragma unroll
  for (int ts = 0; ts < 2; ++ts)
#pragma unroll
    for (int js = 0; js < 4; ++js)
#pragma unroll
      for (int g = 0; g < 3; ++g) acc[ts][js][g] = (f32x4){0.f, 0.f, 0.f, 0.f};

#pragma unroll
  for (int kc = 0; kc < 2; ++kc) {
    const int k0 = kc * 32 + q * 8;
    short8 ah[2], al[2];
#pragma unroll
    for (int ts = 0; ts < 2; ++ts) {
      size_t ax = (size_t)(t0 + ts * 16 + m) * KDIM + k0;
      ah[ts] = *(const short8*)&xhi[ax];
      al[ts] = *(const short8*)&xlo[ax];
    }
    // 12 steps: s = js*3 + g; rolling window of 3 buffers, prefetch depth 2
    short8 bh[3], bl[3];
#pragma unroll
    for (int pf = 0; pf < 2; ++pf) {
      const int js = pf / 3, g = pf % 3;
      size_t bx = (size_t)(g * HDIM + j0 + js * 16 + m) * KDIM + k0;
      bh[pf] = *(const short8*)&whi[bx];
      bl[pf] = *(const short8*)&wlo[bx];
    }
#pragma unroll
    for (int s = 0; s < 12; ++s) {
      if (s + 2 < 12) {
        const int s2 = s + 2;
        const int js2 = s2 / 3, g2 = s2 % 3;
        size_t bx = (size_t)(g2 * HDIM + j0 + js2 * 16 + m) * KDIM + k0;
        bh[s2 % 3] = *(const short8*)&whi[bx];
        bl[s2 % 3] = *(const short8*)&wlo[bx];
      }
      const int js = s / 3, g = s % 3;
      const short8 B0 = bh[s % 3];
      const short8 B1 = bl[s % 3];
#pragma unroll
      for (int ts = 0; ts < 2; ++ts) {
        acc[ts][js][g] = __builtin_amdgcn_mfma_f32_16x16x32_bf16(ah[ts], B0, acc[ts][js][g], 0, 0, 0);
        acc[ts][js][g] = __builtin_amdgcn_mfma_f32_16x16x32_bf16(al[ts], B0, acc[ts][js][g], 0, 0, 0);
        acc[ts][js][g] = __builtin_amdgcn_mfma_f32_16x16x32_bf16(ah[ts], B1, acc[ts][js][g], 0, 0, 0);
      }
    }
  }

  // epilogue: gates already exp2-args -> h -> LDS (stride 65)
#pragma unroll
  for (int js = 0; js < 4; ++js) {
    const int j = j0 + js * 16 + m;
    float bi = bsc[j];
    float bg = bsc[HDIM + j];
    float bo = bsc[2 * HDIM + j];
#pragma unroll
    for (int ts = 0; ts < 2; ++ts) {
#pragma unroll
      for (int r = 0; r < 4; ++r) {
        float ea = EXP2(acc[ts][js][0][r] + bi);          // e^-i
        float eb = EXP2(acc[ts][js][1][r] + bg);          // e^-2g
        float c = (1.0f - eb) * rcpf((1.0f + ea) * (1.0f + eb));   // sig(i)tanh(g)
        float ec = EXP2(acc[ts][js][2][r] + bo);          // e^-o
        float ed = EXP2(S2 * c);                          // e^-2c
        float h = (1.0f - ed) * rcpf((1.0f + ec) * (1.0f + ed));   // sig(o)tanh(c)
        int tl = w * 32 + ts * 16 + q * 4 + r;
        hsh[tl * 65 + js * 16 + m] = h;
      }
    }
  }
  __syncthreads();

  // fused projection over this block's 64 j; plain float2 store of partials
  const int tl = tid & 127;
  const int p0 = (tid >> 7) * 2;
  float s0 = 0.f, s1 = 0.f;
#pragma unroll
  for (int cch = 0; cch < 8; ++cch) {
    const float* wp0 = Whr + (size_t)p0 * HDIM + j0 + cch * 8;
    const float* wp1 = Whr + (size_t)(p0 + 1) * HDIM + j0 + cch * 8;
    float4 w0a = *(const float4*)wp0, w0b = *(const float4*)(wp0 + 4);
    float4 w1a = *(const float4*)wp1, w1b = *(const float4*)(wp1 + 4);
    float wa[8] = {w0a.x, w0a.y, w0a.z, w0a.w, w0b.x, w0b.y, w0b.z, w0b.w};
    float wb[8] = {w1a.x, w1a.y, w1a.z, w1a.w, w1b.x, w1b.y, w1b.z, w1b.w};
#pragma unroll
    for (int e = 0; e < 8; ++e) {
      float h = hsh[tl * 65 + cch * 8 + e];
      s0 = fmaf(h, wa[e], s0);
      s1 = fmaf(h, wb[e], s1);
    }
  }
  const int tg = tb * 128 + tl;
  float2 st = {s0, s1};
  *(float2*)&pp[((size_t)jb * TSTEPS + tg) * PDIM + p0] = st;
}

// Reduce 64 partial slices -> y[t][4]. Fully coalesced; grid 32 x 256.
__global__ void reduce64(const float* __restrict__ pp, float* __restrict__ y) {
  const int t = blockIdx.x * 256 + threadIdx.x;
  float sx = 0.f, sy = 0.f, sz = 0.f, sw = 0.f;
#pragma unroll 8
  for (int k = 0; k < 64; ++k) {
    float4 v = ((const float4*)pp)[(size_t)k * TSTEPS + t];
    sx += v.x; sy += v.y; sz += v.z; sw += v.w;
  }
  ((float4*)y)[t] = make_float4(sx, sy, sz, sw);
}

// Layers 1-2 (K=4): 2 timesteps/thread (amortizes the 5 uniform record loads
// over 2x the VALU work), JPB=64, grid = 16 tchunks x 64 jsplits = 1024.
// NO atomics: partial float4 stores to pp[jsp][t][4] (coalesced).
__global__ __launch_bounds__(256, 4)
void lstm_small(const float* __restrict__ xin, const float* __restrict__ cpk,
                float* __restrict__ pp) {
  const int tid = threadIdx.x;
  const int tc = blockIdx.x >> 6;           // 0..15
  const int jsp = blockIdx.x & 63;          // 0..63
  const int j0 = jsp * 64;
  const int ta = tc * 512 + tid;
  const int tb2 = ta + 256;

  float4 xa = ((const float4*)xin)[ta];
  float4 xb = ((const float4*)xin)[tb2];
  float a0 = 0.f, a1 = 0.f, a2 = 0.f, a3 = 0.f;
  float b0 = 0.f, b1 = 0.f, b2 = 0.f, b3 = 0.f;

#pragma unroll 4
  for (int jj = 0; jj < 64; ++jj) {
    const float* cb = cpk + (size_t)(j0 + jj) * 20;
    float4 wi = *(const float4*)(cb + 0);
    float4 wg = *(const float4*)(cb + 4);
    float4 wo = *(const float4*)(cb + 8);
    float4 bb = *(const float4*)(cb + 12);
    float4 wr = *(const float4*)(cb + 16);
    // timestep a
    float gi = bb.x, gg = bb.y, go = bb.z;
    gi = fmaf(xa.x, wi.x, gi); gi = fmaf(xa.y, wi.y, gi);
    gi = fmaf(xa.z, wi.z, gi); gi = fmaf(xa.w, wi.w, gi);
    gg = fmaf(xa.x, wg.x, gg); gg = fmaf(xa.y, wg.y, gg);
    gg = fmaf(xa.z, wg.z, gg); gg = fmaf(xa.w, wg.w, gg);
    go = fmaf(xa.x, wo.x, go); go = fmaf(xa.y, wo.y, go);
    go = fmaf(xa.z, wo.z, go); go = fmaf(xa.w, wo.w, go);
    float ea = EXP2(gi), eb = EXP2(gg);
    float c = (1.0f - eb) * rcpf((1.0f + ea) * (1.0f + eb));
    float ec = EXP2(go), ed = EXP2(S2 * c);
    float h = (1.0f - ed) * rcpf((1.0f + ec) * (1.0f + ed));
    a0 = fmaf(h, wr.x, a0); a1 = fmaf(h, wr.y, a1);
    a2 = fmaf(h, wr.z, a2); a3 = fmaf(h, wr.w, a3);
    // timestep b
    gi = bb.x; gg = bb.y; go = bb.z;
    gi = fmaf(xb.x, wi.x, gi); gi = fmaf(xb.y, wi.y, gi);
    gi = fmaf(xb.z, wi.z, gi); gi = fmaf(xb.w, wi.w, gi);
    gg = fmaf(xb.x, wg.x, gg); gg = fmaf(xb.y, wg.y, gg);
    gg = fmaf(xb.z, wg.z, gg); gg = fmaf(xb.w, wg.w, gg);
    go = fmaf(xb.x, wo.x, go); go = fmaf(xb.y, wo.y, go);
    go = fmaf(xb.z, wo.z, go); go = fmaf(xb.w, wo.w, go);
    ea = EXP2(gi); eb = EXP2(gg);
    c = (1.0f - eb) * rcpf((1.0f + ea) * (1.0f + eb));
    ec = EXP2(go); ed = EXP2(S2 * c);
    h = (1.0f - ed) * rcpf((1.0f + ec) * (1.0f + ed));
    b0 = fmaf(h, wr.x, b0); b1 = fmaf(h, wr.y, b1);
    b2 = fmaf(h, wr.z, b2); b3 = fmaf(h, wr.w, b3);
  }

  ((float4*)pp)[(size_t)jsp * TSTEPS + ta]  = make_float4(a0, a1, a2, a3);
  ((float4*)pp)[(size_t)jsp * TSTEPS + tb2] = make_float4(b0, b1, b2, b3);
}

extern "C" void kernel_launch(void* const* d_in, const int* in_sizes, int n_in,
                              void* d_out, int out_size, void* d_ws, size_t ws_size,
                              hipStream_t stream) {
  const float* x    = (const float*)d_in[0];
  const float* Wih0 = (const float*)d_in[1];
  const float* bih0 = (const float*)d_in[3];
  const float* bhh0 = (const float*)d_in[4];
  const float* Whr0 = (const float*)d_in[5];
  const float* Wih1 = (const float*)d_in[6];
  const float* bih1 = (const float*)d_in[8];
  const float* bhh1 = (const float*)d_in[9];
  const float* Whr1 = (const float*)d_in[10];
  const float* Wih2 = (const float*)d_in[11];
  const float* bih2 = (const float*)d_in[13];
  const float* bhh2 = (const float*)d_in[14];
  const float* Whr2 = (const float*)d_in[15];
  float* out = (float*)d_out;
  float* ws = (float*)d_ws;
  float* pp = ws + WS_PP;

  prep_kernel<<<dim3(1360), dim3(256), 0, stream>>>(
      x, Wih0, bih0, bhh0, Wih1, bih1, bhh1, Whr1, Wih2, bih2, bhh2, Whr2, ws);

  lstm_layer0_mfma<<<dim3(4096), dim3(256), 0, stream>>>(
      (const u16*)(ws + WS_XHI), (const u16*)(ws + WS_XLO),
      (const u16*)(ws + WS_WHI), (const u16*)(ws + WS_WLO),
      ws + WS_BSC, Whr0, pp);
  reduce64<<<dim3(32), dim3(256), 0, stream>>>(pp, ws + WS_Y0);

  lstm_small<<<dim3(1024), dim3(256), 0, stream>>>(ws + WS_Y0, ws + WS_C1, pp);
  reduce64<<<dim3(32), dim3(256), 0, stream>>>(pp, ws + WS_Y1);

  lstm_small<<<dim3(1024), dim3(256), 0, stream>>>(ws + WS_Y1, ws + WS_C2, pp);
  reduce64<<<dim3(32), dim3(256), 0, stream>>>(pp, out);
}

// Round 7
// 238.402 us; speedup vs baseline: 1.3559x; 1.2554x over previous
//
#include <hip/hip_runtime.h>

#define TSTEPS 8192
#define HDIM 4096
#define PDIM 4
#define KDIM 64

typedef unsigned short u16;
typedef __attribute__((ext_vector_type(8))) short short8;
typedef __attribute__((ext_vector_type(4))) float f32x4;

#define S1 -1.44269504089f   // -log2(e)
#define S2 -2.88539008177f   // -2*log2(e)

#if __has_builtin(__builtin_amdgcn_exp2f)
#define EXP2(x) __builtin_amdgcn_exp2f(x)
#else
#define EXP2(x) exp2f(x)
#endif
__device__ __forceinline__ float rcpf(float x) { return __builtin_amdgcn_rcpf(x); }

// async global->LDS DMA, 16B per lane; LDS dest = uniform base + lane*16
__device__ __forceinline__ void gload16(const void* g, void* l) {
  __builtin_amdgcn_global_load_lds((const __attribute__((address_space(1))) unsigned int*)g,
                                   (__attribute__((address_space(3))) unsigned int*)l,
                                   16, 0, 0);
}

__device__ __forceinline__ u16 bf16_rne(float f) {
  unsigned u = __float_as_uint(f);
  u += 0x7FFF + ((u >> 16) & 1);
  return (u16)(u >> 16);
}
__device__ __forceinline__ void hilo(float v, u16& h, u16& l) {
  h = bf16_rne(v);
  l = bf16_rne(v - __uint_as_float((unsigned)h << 16));
}

// ---- workspace layout (float offsets) ----
#define WS_Y0   0
#define WS_Y1   32768
#define WS_BSC  65536
#define WS_C1   77824
#define WS_C2   159744
#define WS_XHI  241664
#define WS_XLO  503808
#define WS_WHI  765952
#define WS_WLO  1159168
#define WS_PP   1552384
// total 3649536 floats = 14.6 MB

// One-shot prep: bf16 hi/lo of x and W_ih0 (i,g,o rows, PRE-SCALED by S1/S2 so
// gates feed v_exp directly), scaled merged biases, packed per-j records for
// layers 1/2.
__global__ void prep_kernel(const float* __restrict__ x,
                            const float* __restrict__ Wih0, const float* __restrict__ bih0,
                            const float* __restrict__ bhh0,
                            const float* __restrict__ Wih1, const float* __restrict__ bih1,
                            const float* __restrict__ bhh1, const float* __restrict__ Whr1,
                            const float* __restrict__ Wih2, const float* __restrict__ bih2,
                            const float* __restrict__ bhh2, const float* __restrict__ Whr2,
                            float* __restrict__ ws) {
  const int i = blockIdx.x * 256 + threadIdx.x;
  u16* xhi = (u16*)(ws + WS_XHI);
  u16* xlo = (u16*)(ws + WS_XLO);
  u16* whi = (u16*)(ws + WS_WHI);
  u16* wlo = (u16*)(ws + WS_WLO);

  if (i < 131072) {                       // x: 131072 float4 units, unscaled
    float4 v = *(const float4*)&x[i * 4];
    float val[4] = {v.x, v.y, v.z, v.w};
    u16 h[4], l[4];
#pragma unroll
    for (int e = 0; e < 4; ++e) hilo(val[e], h[e], l[e]);
    *(ushort4*)&xhi[i * 4] = make_ushort4(h[0], h[1], h[2], h[3]);
    *(ushort4*)&xlo[i * 4] = make_ushort4(l[0], l[1], l[2], l[3]);
  } else if (i < 327680) {                // W_ih0: 196608 float4 units, scaled
    int f = i - 131072;
    int el4 = f * 4;
    int r = el4 >> 6;                     // packed row 0..12287 ([gate][j])
    int k4 = el4 & 63;
    int gate = r >> 12, jr = r & 4095;
    int src = (gate == 0) ? jr : (gate + 1) * HDIM + jr;   // i,g,o = rows 0,2H,3H
    float sc = (gate == 1) ? S2 : S1;
    float4 v = *(const float4*)&Wih0[(size_t)src * KDIM + k4];
    float val[4] = {sc * v.x, sc * v.y, sc * v.z, sc * v.w};
    u16 h[4], l[4];
#pragma unroll
    for (int e = 0; e < 4; ++e) hilo(val[e], h[e], l[e]);
    *(ushort4*)&whi[r * KDIM + k4] = make_ushort4(h[0], h[1], h[2], h[3]);
    *(ushort4*)&wlo[r * KDIM + k4] = make_ushort4(l[0], l[1], l[2], l[3]);
  } else if (i < 339968) {                // bsc[3][4096], scaled merged bias
    int f = i - 327680;
    int g = f >> 12, j = f & 4095;
    int src = (g == 0) ? j : (g + 1) * HDIM + j;
    float sc = (g == 1) ? S2 : S1;
    ws[WS_BSC + f] = sc * (bih0[src] + bhh0[src]);
  } else if (i < 348160) {                // c1/c2 packed records (20 floats/j)
    int f = i - 339968;
    const float* Wih = (f < 4096) ? Wih1 : Wih2;
    const float* bih = (f < 4096) ? bih1 : bih2;
    const float* bhh = (f < 4096) ? bhh1 : bhh2;
    const float* Whr = (f < 4096) ? Whr1 : Whr2;
    float* c = ws + ((f < 4096) ? WS_C1 : WS_C2);
    int j = f & 4095;
    float4 wi = *(const float4*)&Wih[(size_t)j * 4];
    float4 wg = *(const float4*)&Wih[(size_t)(2 * HDIM + j) * 4];
    float4 wo = *(const float4*)&Wih[(size_t)(3 * HDIM + j) * 4];
    float* cb = c + j * 20;
    *(float4*)(cb + 0)  = make_float4(S1 * wi.x, S1 * wi.y, S1 * wi.z, S1 * wi.w);
    *(float4*)(cb + 4)  = make_float4(S2 * wg.x, S2 * wg.y, S2 * wg.z, S2 * wg.w);
    *(float4*)(cb + 8)  = make_float4(S1 * wo.x, S1 * wo.y, S1 * wo.z, S1 * wo.w);
    *(float4*)(cb + 12) = make_float4(S1 * (bih[j] + bhh[j]),
                                      S2 * (bih[2 * HDIM + j] + bhh[2 * HDIM + j]),
                                      S1 * (bih[3 * HDIM + j] + bhh[3 * HDIM + j]), 0.f);
    *(float4*)(cb + 16) = make_float4(Whr[j], Whr[HDIM + j], Whr[2 * HDIM + j], Whr[3 * HDIM + j]);
  }
}

// Layer 0: single-shot async-staged MFMA. Block = 4 waves = 128t x 64j x 3
// gates; grid 4096 (64 tb x 64 jb). LDS 64 KB: x-hi 16K + W-hi 24K + W-lo 24K,
// staged via global_load_lds (64 x 1KB units, 16/wave), ONE barrier, then
// ds_read_b128 -> MFMA burst. x-lo fragments load global->VGPR directly
// (8/wave, hoistable). Chunk-XOR swizzle (stored = logical ^ (row&7)) makes
// both the wave-uniform staging layout and conflict-free b128 reads work:
// row stride is exactly 32 banks, so unswizzled reads would be 16-way.
// NO atomics: projection partials stored plain to pp[jb][t][4].
__global__ __launch_bounds__(256, 2)
void lstm_layer0_mfma(const u16* __restrict__ xhi, const u16* __restrict__ xlo,
                      const u16* __restrict__ whi, const u16* __restrict__ wlo,
                      const float* __restrict__ bsc, const float* __restrict__ Whr,
                      float* __restrict__ pp) {
  __shared__ __align__(16) char smem[65536];
  u16* lx_hi = (u16*)smem;                 // [128 t][64 k]  (swizzled chunks)
  u16* lw_hi = (u16*)(smem + 16384);       // [192 rows = g*64+j][64 k]
  u16* lw_lo = (u16*)(smem + 40960);
  float* hsh = (float*)smem;               // reused after barrier: [128][68]

  const int tid = threadIdx.x;
  const int w = tid >> 6, lane = tid & 63;
  const int m = lane & 15, q = lane >> 4;
  const int jb = blockIdx.x & 63, tb = blockIdx.x >> 6;
  const int j0 = jb * 64;
  const int t0 = tb * 128;

  // ---- async stage: 64 units of 1KB (8 rows of 128B each), wave w -> u[w*16..)
  const int r8 = lane >> 3;                       // row within 8-row group
  const int swo = ((lane & 7) ^ r8) * 8;          // swizzled logical chunk (u16)
#pragma unroll
  for (int ui = 0; ui < 16; ++ui) {
    const int u = w * 16 + ui;
    const u16* g;
    char* l;
    if (u < 16) {                                 // x-hi rows t0 + u*8 ..
      g = xhi + (size_t)(t0 + u * 8 + r8) * 64 + swo;
      l = smem + u * 1024;
    } else if (u < 40) {                          // W-hi: gate uu>>3, j-group uu&7
      int uu = u - 16;
      g = whi + (size_t)((uu >> 3) * HDIM + j0 + (uu & 7) * 8 + r8) * 64 + swo;
      l = smem + 16384 + uu * 1024;
    } else {                                      // W-lo
      int uu = u - 40;
      g = wlo + (size_t)((uu >> 3) * HDIM + j0 + (uu & 7) * 8 + r8) * 64 + swo;
      l = smem + 40960 + uu * 1024;
    }
    gload16(g, l);
  }

  f32x4 acc[2][4][3];
#pragma unroll
  for (int ts = 0; ts < 2; ++ts)
#pragma unroll
    for (int js = 0; js < 4; ++js)
#pragma unroll
      for (int g = 0; g < 3; ++g) acc[ts][js][g] = (f32x4){0.f, 0.f, 0.f, 0.f};

  // x-lo fragments: direct global->VGPR (independent of LDS; issues early)
  short8 al[2][2];
#pragma unroll
  for (int kc = 0; kc < 2; ++kc)
#pragma unroll
    for (int ts = 0; ts < 2; ++ts)
      al[kc][ts] = *(const short8*)&xlo[(size_t)(t0 + w * 32 + ts * 16 + m) * KDIM + kc * 32 + q * 8];

  __syncthreads();   // drains the global_load_lds queue (vmcnt0 + barrier)

  // ---- MFMA burst from LDS
#pragma unroll
  for (int kc = 0; kc < 2; ++kc) {
    const int cs = ((kc * 4 + q) ^ (m & 7)) * 8;  // swizzled chunk offset
    short8 ah[2];
#pragma unroll
    for (int ts = 0; ts < 2; ++ts)
      ah[ts] = *(const short8*)&lx_hi[(w * 32 + ts * 16 + m) * 64 + cs];
#pragma unroll
    for (int js = 0; js < 4; ++js) {
#pragma unroll
      for (int g = 0; g < 3; ++g) {
        const int roff = (g * 64 + js * 16 + m) * 64 + cs;
        short8 bh = *(const short8*)&lw_hi[roff];
        short8 bl = *(const short8*)&lw_lo[roff];
#pragma unroll
        for (int ts = 0; ts < 2; ++ts) {
          acc[ts][js][g] = __builtin_amdgcn_mfma_f32_16x16x32_bf16(ah[ts], bh, acc[ts][js][g], 0, 0, 0);
          acc[ts][js][g] = __builtin_amdgcn_mfma_f32_16x16x32_bf16(al[kc][ts], bh, acc[ts][js][g], 0, 0, 0);
          acc[ts][js][g] = __builtin_amdgcn_mfma_f32_16x16x32_bf16(ah[ts], bl, acc[ts][js][g], 0, 0, 0);
        }
      }
    }
  }

  // ---- activations into registers (LDS still holds W; no writes yet)
  float hreg[2][4][4];
#pragma unroll
  for (int js = 0; js < 4; ++js) {
    const int j = j0 + js * 16 + m;
    float bi = bsc[j];
    float bg = bsc[HDIM + j];
    float bo = bsc[2 * HDIM + j];
#pragma unroll
    for (int ts = 0; ts < 2; ++ts) {
#pragma unroll
      for (int r = 0; r < 4; ++r) {
        float ea = EXP2(acc[ts][js][0][r] + bi);          // e^-i
        float eb = EXP2(acc[ts][js][1][r] + bg);          // e^-2g
        float c = (1.0f - eb) * rcpf((1.0f + ea) * (1.0f + eb));   // sig(i)tanh(g)
        float ec = EXP2(acc[ts][js][2][r] + bo);          // e^-o
        float ed = EXP2(S2 * c);                          // e^-2c
        hreg[ts][js][r] = (1.0f - ed) * rcpf((1.0f + ec) * (1.0f + ed));
      }
    }
  }
  __syncthreads();   // all LDS fragment reads done -> safe to reuse as hsh

  // h -> LDS, stride 68 floats (17*tl mod 32 spans all banks for b128 reads)
#pragma unroll
  for (int js = 0; js < 4; ++js)
#pragma unroll
    for (int ts = 0; ts < 2; ++ts)
#pragma unroll
      for (int r = 0; r < 4; ++r)
        hsh[(w * 32 + ts * 16 + q * 4 + r) * 68 + js * 16 + m] = hreg[ts][js][r];
  __syncthreads();

  // fused projection over this block's 64 j; plain float2 store of partials
  const int tl = tid & 127;
  const int p0 = (tid >> 7) * 2;
  float s0 = 0.f, s1 = 0.f;
#pragma unroll
  for (int cch = 0; cch < 8; ++cch) {
    const float* wp0 = Whr + (size_t)p0 * HDIM + j0 + cch * 8;
    const float* wp1 = Whr + (size_t)(p0 + 1) * HDIM + j0 + cch * 8;
    float4 w0a = *(const float4*)wp0, w0b = *(const float4*)(wp0 + 4);
    float4 w1a = *(const float4*)wp1, w1b = *(const float4*)(wp1 + 4);
    float4 ha = *(const float4*)&hsh[tl * 68 + cch * 8];
    float4 hb = *(const float4*)&hsh[tl * 68 + cch * 8 + 4];
    float wa[8] = {w0a.x, w0a.y, w0a.z, w0a.w, w0b.x, w0b.y, w0b.z, w0b.w};
    float wb[8] = {w1a.x, w1a.y, w1a.z, w1a.w, w1b.x, w1b.y, w1b.z, w1b.w};
    float hv[8] = {ha.x, ha.y, ha.z, ha.w, hb.x, hb.y, hb.z, hb.w};
#pragma unroll
    for (int e = 0; e < 8; ++e) {
      s0 = fmaf(hv[e], wa[e], s0);
      s1 = fmaf(hv[e], wb[e], s1);
    }
  }
  const int tg = tb * 128 + tl;
  float2 st = {s0, s1};
  *(float2*)&pp[((size_t)jb * TSTEPS + tg) * PDIM + p0] = st;
}

// Reduce 64 partial slices -> y[t][4]; one thread per (t,p), fully coalesced.
__global__ void reduce64(const float* __restrict__ pp, float* __restrict__ y) {
  const int i = blockIdx.x * 256 + threadIdx.x;   // 0..32767 = t*4 + p
  float s = 0.f;
#pragma unroll 16
  for (int k = 0; k < 64; ++k) s += pp[(size_t)k * (TSTEPS * PDIM) + i];
  y[i] = s;
}

// Layers 1-2 (K=4): records staged to LDS (5 KB) -> j-loop operands are
// conflict-free LDS broadcasts; 2 timesteps/thread amortizes them further.
// Grid = 16 tchunks x 64 jsplits = 1024; plain partial stores (no atomics).
__global__ __launch_bounds__(256, 4)
void lstm_small(const float* __restrict__ xin, const float* __restrict__ cpk,
                float* __restrict__ pp) {
  __shared__ __align__(16) float rec[1280];       // 64 records x 20 floats
  const int tid = threadIdx.x;
  const int tc = blockIdx.x >> 6;
  const int jsp = blockIdx.x & 63;
  const int j0 = jsp * 64;

  for (int i = tid; i < 320; i += 256)
    ((float4*)rec)[i] = ((const float4*)(cpk + (size_t)j0 * 20))[i];

  const int ta = tc * 512 + tid;
  const int tb2 = ta + 256;
  float4 xa = ((const float4*)xin)[ta];
  float4 xb = ((const float4*)xin)[tb2];
  float a0 = 0.f, a1 = 0.f, a2 = 0.f, a3 = 0.f;
  float b0 = 0.f, b1 = 0.f, b2 = 0.f, b3 = 0.f;
  __syncthreads();

#pragma unroll 4
  for (int jj = 0; jj < 64; ++jj) {
    const float* cb = rec + jj * 20;
    float4 wi = *(const float4*)(cb + 0);
    float4 wg = *(const float4*)(cb + 4);
    float4 wo = *(const float4*)(cb + 8);
    float4 bb = *(const float4*)(cb + 12);
    float4 wr = *(const float4*)(cb + 16);
    // timestep a
    float gi = bb.x, gg = bb.y, go = bb.z;
    gi = fmaf(xa.x, wi.x, gi); gi = fmaf(xa.y, wi.y, gi);
    gi = fmaf(xa.z, wi.z, gi); gi = fmaf(xa.w, wi.w, gi);
    gg = fmaf(xa.x, wg.x, gg); gg = fmaf(xa.y, wg.y, gg);
    gg = fmaf(xa.z, wg.z, gg); gg = fmaf(xa.w, wg.w, gg);
    go = fmaf(xa.x, wo.x, go); go = fmaf(xa.y, wo.y, go);
    go = fmaf(xa.z, wo.z, go); go = fmaf(xa.w, wo.w, go);
    float ea = EXP2(gi), eb = EXP2(gg);
    float c = (1.0f - eb) * rcpf((1.0f + ea) * (1.0f + eb));
    float ec = EXP2(go), ed = EXP2(S2 * c);
    float h = (1.0f - ed) * rcpf((1.0f + ec) * (1.0f + ed));
    a0 = fmaf(h, wr.x, a0); a1 = fmaf(h, wr.y, a1);
    a2 = fmaf(h, wr.z, a2); a3 = fmaf(h, wr.w, a3);
    // timestep b
    gi = bb.x; gg = bb.y; go = bb.z;
    gi = fmaf(xb.x, wi.x, gi); gi = fmaf(xb.y, wi.y, gi);
    gi = fmaf(xb.z, wi.z, gi); gi = fmaf(xb.w, wi.w, gi);
    gg = fmaf(xb.x, wg.x, gg); gg = fmaf(xb.y, wg.y, gg);
    gg = fmaf(xb.z, wg.z, gg); gg = fmaf(xb.w, wg.w, gg);
    go = fmaf(xb.x, wo.x, go); go = fmaf(xb.y, wo.y, go);
    go = fmaf(xb.z, wo.z, go); go = fmaf(xb.w, wo.w, go);
    ea = EXP2(gi); eb = EXP2(gg);
    c = (1.0f - eb) * rcpf((1.0f + ea) * (1.0f + eb));
    ec = EXP2(go); ed = EXP2(S2 * c);
    h = (1.0f - ed) * rcpf((1.0f + ec) * (1.0f + ed));
    b0 = fmaf(h, wr.x, b0); b1 = fmaf(h, wr.y, b1);
    b2 = fmaf(h, wr.z, b2); b3 = fmaf(h, wr.w, b3);
  }

  ((float4*)pp)[(size_t)jsp * TSTEPS + ta]  = make_float4(a0, a1, a2, a3);
  ((float4*)pp)[(size_t)jsp * TSTEPS + tb2] = make_float4(b0, b1, b2, b3);
}

extern "C" void kernel_launch(void* const* d_in, const int* in_sizes, int n_in,
                              void* d_out, int out_size, void* d_ws, size_t ws_size,
                              hipStream_t stream) {
  const float* x    = (const float*)d_in[0];
  const float* Wih0 = (const float*)d_in[1];
  const float* bih0 = (const float*)d_in[3];
  const float* bhh0 = (const float*)d_in[4];
  const float* Whr0 = (const float*)d_in[5];
  const float* Wih1 = (const float*)d_in[6];
  const float* bih1 = (const float*)d_in[8];
  const float* bhh1 = (const float*)d_in[9];
  const float* Whr1 = (const float*)d_in[10];
  const float* Wih2 = (const float*)d_in[11];
  const float* bih2 = (const float*)d_in[13];
  const float* bhh2 = (const float*)d_in[14];
  const float* Whr2 = (const float*)d_in[15];
  float* out = (float*)d_out;
  float* ws = (float*)d_ws;
  float* pp = ws + WS_PP;

  prep_kernel<<<dim3(1360), dim3(256), 0, stream>>>(
      x, Wih0, bih0, bhh0, Wih1, bih1, bhh1, Whr1, Wih2, bih2, bhh2, Whr2, ws);

  lstm_layer0_mfma<<<dim3(4096), dim3(256), 0, stream>>>(
      (const u16*)(ws + WS_XHI), (const u16*)(ws + WS_XLO),
      (const u16*)(ws + WS_WHI), (const u16*)(ws + WS_WLO),
      ws + WS_BSC, Whr0, pp);
  reduce64<<<dim3(128), dim3(256), 0, stream>>>(pp, ws + WS_Y0);

  lstm_small<<<dim3(1024), dim3(256), 0, stream>>>(ws + WS_Y0, ws + WS_C1, pp);
  reduce64<<<dim3(128), dim3(256), 0, stream>>>(pp, ws + WS_Y1);

  lstm_small<<<dim3(1024), dim3(256), 0, stream>>>(ws + WS_Y1, ws + WS_C2, pp);
  reduce64<<<dim3(128), dim3(256), 0, stream>>>(pp, out);
}

// Round 8
// 232.758 us; speedup vs baseline: 1.3888x; 1.0242x over previous
//
#include <hip/hip_runtime.h>

#define TSTEPS 8192
#define HDIM 4096
#define PDIM 4
#define KDIM 64

typedef unsigned short u16;
typedef __attribute__((ext_vector_type(8))) short short8;
typedef __attribute__((ext_vector_type(4))) float f32x4;

#define S1 -1.44269504089f   // -log2(e)
#define S2 -2.88539008177f   // -2*log2(e)

#if __has_builtin(__builtin_amdgcn_exp2f)
#define EXP2(x) __builtin_amdgcn_exp2f(x)
#else
#define EXP2(x) exp2f(x)
#endif
__device__ __forceinline__ float rcpf(float x) { return __builtin_amdgcn_rcpf(x); }

// async global->LDS DMA, 16B per lane; LDS dest = uniform base + lane*16
__device__ __forceinline__ void gload16(const void* g, void* l) {
  __builtin_amdgcn_global_load_lds((const __attribute__((address_space(1))) unsigned int*)g,
                                   (__attribute__((address_space(3))) unsigned int*)l,
                                   16, 0, 0);
}

__device__ __forceinline__ u16 bf16_rne(float f) {
  unsigned u = __float_as_uint(f);
  u += 0x7FFF + ((u >> 16) & 1);
  return (u16)(u >> 16);
}
__device__ __forceinline__ void hilo(float v, u16& h, u16& l) {
  h = bf16_rne(v);
  l = bf16_rne(v - __uint_as_float((unsigned)h << 16));
}

// ---- workspace layout (float offsets) ----
#define WS_Y0   0
#define WS_Y1   32768
#define WS_BSC  65536
#define WS_C1   77824
#define WS_C2   159744
#define WS_XHI  241664
#define WS_XLO  503808
#define WS_WHI  765952
#define WS_WLO  1159168
#define WS_PP   1552384
// total 3649536 floats = 14.6 MB

// One-shot prep: bf16 hi/lo of x and W_ih0 (i,g,o rows, PRE-SCALED by S1/S2 so
// gates feed v_exp directly), scaled merged biases, packed per-j records for
// layers 1/2.
__global__ void prep_kernel(const float* __restrict__ x,
                            const float* __restrict__ Wih0, const float* __restrict__ bih0,
                            const float* __restrict__ bhh0,
                            const float* __restrict__ Wih1, const float* __restrict__ bih1,
                            const float* __restrict__ bhh1, const float* __restrict__ Whr1,
                            const float* __restrict__ Wih2, const float* __restrict__ bih2,
                            const float* __restrict__ bhh2, const float* __restrict__ Whr2,
                            float* __restrict__ ws) {
  const int i = blockIdx.x * 256 + threadIdx.x;
  u16* xhi = (u16*)(ws + WS_XHI);
  u16* xlo = (u16*)(ws + WS_XLO);
  u16* whi = (u16*)(ws + WS_WHI);
  u16* wlo = (u16*)(ws + WS_WLO);

  if (i < 131072) {                       // x: 131072 float4 units, unscaled
    float4 v = *(const float4*)&x[i * 4];
    float val[4] = {v.x, v.y, v.z, v.w};
    u16 h[4], l[4];
#pragma unroll
    for (int e = 0; e < 4; ++e) hilo(val[e], h[e], l[e]);
    *(ushort4*)&xhi[i * 4] = make_ushort4(h[0], h[1], h[2], h[3]);
    *(ushort4*)&xlo[i * 4] = make_ushort4(l[0], l[1], l[2], l[3]);
  } else if (i < 327680) {                // W_ih0: 196608 float4 units, scaled
    int f = i - 131072;
    int el4 = f * 4;
    int r = el4 >> 6;                     // packed row 0..12287 ([gate][j])
    int k4 = el4 & 63;
    int gate = r >> 12, jr = r & 4095;
    int src = (gate == 0) ? jr : (gate + 1) * HDIM + jr;   // i,g,o = rows 0,2H,3H
    float sc = (gate == 1) ? S2 : S1;
    float4 v = *(const float4*)&Wih0[(size_t)src * KDIM + k4];
    float val[4] = {sc * v.x, sc * v.y, sc * v.z, sc * v.w};
    u16 h[4], l[4];
#pragma unroll
    for (int e = 0; e < 4; ++e) hilo(val[e], h[e], l[e]);
    *(ushort4*)&whi[r * KDIM + k4] = make_ushort4(h[0], h[1], h[2], h[3]);
    *(ushort4*)&wlo[r * KDIM + k4] = make_ushort4(l[0], l[1], l[2], l[3]);
  } else if (i < 339968) {                // bsc[3][4096], scaled merged bias
    int f = i - 327680;
    int g = f >> 12, j = f & 4095;
    int src = (g == 0) ? j : (g + 1) * HDIM + j;
    float sc = (g == 1) ? S2 : S1;
    ws[WS_BSC + f] = sc * (bih0[src] + bhh0[src]);
  } else if (i < 348160) {                // c1/c2 packed records (20 floats/j)
    int f = i - 339968;
    const float* Wih = (f < 4096) ? Wih1 : Wih2;
    const float* bih = (f < 4096) ? bih1 : bih2;
    const float* bhh = (f < 4096) ? bhh1 : bhh2;
    const float* Whr = (f < 4096) ? Whr1 : Whr2;
    float* c = ws + ((f < 4096) ? WS_C1 : WS_C2);
    int j = f & 4095;
    float4 wi = *(const float4*)&Wih[(size_t)j * 4];
    float4 wg = *(const float4*)&Wih[(size_t)(2 * HDIM + j) * 4];
    float4 wo = *(const float4*)&Wih[(size_t)(3 * HDIM + j) * 4];
    float* cb = c + j * 20;
    *(float4*)(cb + 0)  = make_float4(S1 * wi.x, S1 * wi.y, S1 * wi.z, S1 * wi.w);
    *(float4*)(cb + 4)  = make_float4(S2 * wg.x, S2 * wg.y, S2 * wg.z, S2 * wg.w);
    *(float4*)(cb + 8)  = make_float4(S1 * wo.x, S1 * wo.y, S1 * wo.z, S1 * wo.w);
    *(float4*)(cb + 12) = make_float4(S1 * (bih[j] + bhh[j]),
                                      S2 * (bih[2 * HDIM + j] + bhh[2 * HDIM + j]),
                                      S1 * (bih[3 * HDIM + j] + bhh[3 * HDIM + j]), 0.f);
    *(float4*)(cb + 16) = make_float4(Whr[j], Whr[HDIM + j], Whr[2 * HDIM + j], Whr[3 * HDIM + j]);
  }
}

// Layer 0: async-staged MFMA, W amortized over TWO 128-t tiles per block.
// Block = 4 waves, covers 256t x 64j; grid = 32 tbb x 64 jb = 2048.
// LDS 64KB: W-hi 24K @0, W-lo 24K @24576, x-hi tile 16K @49152 (restaged for
// tile 1 during tile-0 epilogue). x-lo lives in VGPRs. Chunk-XOR swizzle
// (stored chunk = logical ^ (row&7)) for wave-uniform DMA + conflict-free
// ds_read_b128 (verified 0 conflicts in r7).
// Projection: in-register js-sum then shfl_xor butterfly over the 16 m-lanes
// (j lives in lanes); lane m==0 stores float4 (t,p0..p3) to pp. No h LDS,
// no extra barriers, no atomics.
__global__ __launch_bounds__(256, 2)
void lstm_layer0_mfma(const u16* __restrict__ xhi, const u16* __restrict__ xlo,
                      const u16* __restrict__ whi, const u16* __restrict__ wlo,
                      const float* __restrict__ bsc, const float* __restrict__ Whr,
                      float* __restrict__ pp) {
  __shared__ __align__(16) char smem[65536];
  u16* lw_hi = (u16*)smem;                 // [192 rows = g*64+j][64 k] swizzled
  u16* lw_lo = (u16*)(smem + 24576);
  u16* lx    = (u16*)(smem + 49152);       // [128 t][64 k] current tile

  const int tid = threadIdx.x;
  const int w = tid >> 6, lane = tid & 63;
  const int m = lane & 15, q = lane >> 4;
  const int jb = blockIdx.x & 63, tbb = blockIdx.x >> 6;
  const int j0 = jb * 64;
  const int t0 = tbb * 256;

  const int r8 = lane >> 3;
  const int swo = ((lane & 7) ^ r8) * 8;

  // ---- stage W (48 x 1KB units) + x tile0 (16 units); 16 units/wave
#pragma unroll
  for (int ui = 0; ui < 16; ++ui) {
    const int u = w * 16 + ui;
    const u16* g;
    char* l;
    if (u < 24) {
      g = whi + (size_t)((u >> 3) * HDIM + j0 + (u & 7) * 8 + r8) * 64 + swo;
      l = smem + u * 1024;
    } else if (u < 48) {
      int uu = u - 24;
      g = wlo + (size_t)((uu >> 3) * HDIM + j0 + (uu & 7) * 8 + r8) * 64 + swo;
      l = smem + 24576 + uu * 1024;
    } else {
      int uu = u - 48;
      g = xhi + (size_t)(t0 + uu * 8 + r8) * 64 + swo;
      l = smem + 49152 + uu * 1024;
    }
    gload16(g, l);
  }

  // per-lane constants reused by both tiles (fly under the DMA)
  float whr_v[4][4];
#pragma unroll
  for (int p = 0; p < 4; ++p)
#pragma unroll
    for (int js = 0; js < 4; ++js)
      whr_v[p][js] = Whr[(size_t)p * HDIM + j0 + js * 16 + m];
  float biv[4], bgv[4], bov[4];
#pragma unroll
  for (int js = 0; js < 4; ++js) {
    const int j = j0 + js * 16 + m;
    biv[js] = bsc[j];
    bgv[js] = bsc[HDIM + j];
    bov[js] = bsc[2 * HDIM + j];
  }

  f32x4 acc[2][4][3];
  short8 al[2][2];

  auto zero_acc = [&]() {
#pragma unroll
    for (int ts = 0; ts < 2; ++ts)
#pragma unroll
      for (int js = 0; js < 4; ++js)
#pragma unroll
        for (int g = 0; g < 3; ++g) acc[ts][js][g] = (f32x4){0.f, 0.f, 0.f, 0.f};
  };
  auto load_al = [&](int tt) {
#pragma unroll
    for (int kc = 0; kc < 2; ++kc)
#pragma unroll
      for (int ts = 0; ts < 2; ++ts)
        al[kc][ts] = *(const short8*)&xlo[(size_t)(t0 + tt * 128 + w * 32 + ts * 16 + m) * KDIM + kc * 32 + q * 8];
  };
  auto compute = [&]() {
#pragma unroll
    for (int kc = 0; kc < 2; ++kc) {
      const int cs = ((kc * 4 + q) ^ (m & 7)) * 8;
      short8 ah[2];
#pragma unroll
      for (int ts = 0; ts < 2; ++ts)
        ah[ts] = *(const short8*)&lx[(w * 32 + ts * 16 + m) * 64 + cs];
#pragma unroll
      for (int js = 0; js < 4; ++js) {
#pragma unroll
        for (int g = 0; g < 3; ++g) {
          const int roff = (g * 64 + js * 16 + m) * 64 + cs;
          short8 bh = *(const short8*)&lw_hi[roff];
          short8 bl = *(const short8*)&lw_lo[roff];
#pragma unroll
          for (int ts = 0; ts < 2; ++ts) {
            acc[ts][js][g] = __builtin_amdgcn_mfma_f32_16x16x32_bf16(ah[ts], bh, acc[ts][js][g], 0, 0, 0);
            acc[ts][js][g] = __builtin_amdgcn_mfma_f32_16x16x32_bf16(al[kc][ts], bh, acc[ts][js][g], 0, 0, 0);
            acc[ts][js][g] = __builtin_amdgcn_mfma_f32_16x16x32_bf16(ah[ts], bl, acc[ts][js][g], 0, 0, 0);
          }
        }
      }
    }
  };
  auto act_proj = [&](int tt) {
    float hreg[2][4][4];
#pragma unroll
    for (int js = 0; js < 4; ++js) {
#pragma unroll
      for (int ts = 0; ts < 2; ++ts) {
#pragma unroll
        for (int r = 0; r < 4; ++r) {
          float ea = EXP2(acc[ts][js][0][r] + biv[js]);       // e^-i
          float eb = EXP2(acc[ts][js][1][r] + bgv[js]);       // e^-2g
          float c = (1.0f - eb) * rcpf((1.0f + ea) * (1.0f + eb));  // sig(i)tanh(g)
          float ec = EXP2(acc[ts][js][2][r] + bov[js]);       // e^-o
          float ed = EXP2(S2 * c);                            // e^-2c
          hreg[ts][js][r] = (1.0f - ed) * rcpf((1.0f + ec) * (1.0f + ed));
        }
      }
    }
    // projection partial over this lane's 4 js, then butterfly over 16 m-lanes
#pragma unroll
    for (int ts = 0; ts < 2; ++ts) {
#pragma unroll
      for (int r = 0; r < 4; ++r) {
        float pv[4];
#pragma unroll
        for (int p = 0; p < 4; ++p) {
          float s = 0.f;
#pragma unroll
          for (int js = 0; js < 4; ++js) s = fmaf(hreg[ts][js][r], whr_v[p][js], s);
#pragma unroll
          for (int ofs = 1; ofs < 16; ofs <<= 1) s += __shfl_xor(s, ofs, 16);
          pv[p] = s;
        }
        if (m == 0) {
          const int t = t0 + tt * 128 + w * 32 + ts * 16 + q * 4 + r;
          *(float4*)&pp[((size_t)jb * TSTEPS + t) * PDIM] = make_float4(pv[0], pv[1], pv[2], pv[3]);
        }
      }
    }
  };

  // ---- tile 0
  load_al(0);
  zero_acc();
  __syncthreads();                 // drain W + x0 DMA
  compute();
  __syncthreads();                 // all x-region reads done
  // ---- stage x tile1 (16 units, 4/wave) while tile-0 epilogue runs
#pragma unroll
  for (int ui = 0; ui < 4; ++ui) {
    const int u = w * 4 + ui;
    gload16(xhi + (size_t)(t0 + 128 + u * 8 + r8) * 64 + swo, smem + 49152 + u * 1024);
  }
  load_al(1);
  act_proj(0);
  zero_acc();
  __syncthreads();                 // drain x1 DMA
  compute();
  act_proj(1);
}

// Reduce 64 partial slices -> y[t][4]; one thread per (t,p), fully coalesced.
__global__ void reduce64(const float* __restrict__ pp, float* __restrict__ y) {
  const int i = blockIdx.x * 256 + threadIdx.x;   // 0..32767 = t*4 + p
  float s = 0.f;
#pragma unroll 16
  for (int k = 0; k < 64; ++k) s += pp[(size_t)k * (TSTEPS * PDIM) + i];
  y[i] = s;
}

// Layers 1-2 (K=4): records staged to LDS (5 KB), 1 timestep/thread,
// grid = 32 tchunks x 64 jsplits = 2048 -> 8 blocks/CU, 8 waves/SIMD
// (launch_bounds(256,8) caps VGPR at 64; kernel needs ~35). Plain partial
// stores (no atomics).
__global__ __launch_bounds__(256, 8)
void lstm_small(const float* __restrict__ xin, const float* __restrict__ cpk,
                float* __restrict__ pp) {
  __shared__ __align__(16) float rec[1280];       // 64 records x 20 floats
  const int tid = threadIdx.x;
  const int tc = blockIdx.x >> 6;                 // 0..31
  const int jsp = blockIdx.x & 63;                // 0..63
  const int j0 = jsp * 64;

  for (int i = tid; i < 320; i += 256)
    ((float4*)rec)[i] = ((const float4*)(cpk + (size_t)j0 * 20))[i];

  const int t = tc * 256 + tid;
  float4 xv = ((const float4*)xin)[t];
  float o0 = 0.f, o1 = 0.f, o2 = 0.f, o3 = 0.f;
  __syncthreads();

#pragma unroll 8
  for (int jj = 0; jj < 64; ++jj) {
    const float* cb = rec + jj * 20;
    float4 wi = *(const float4*)(cb + 0);
    float4 wg = *(const float4*)(cb + 4);
    float4 wo = *(const float4*)(cb + 8);
    float4 bb = *(const float4*)(cb + 12);
    float4 wr = *(const float4*)(cb + 16);
    float gi = bb.x, gg = bb.y, go = bb.z;
    gi = fmaf(xv.x, wi.x, gi); gi = fmaf(xv.y, wi.y, gi);
    gi = fmaf(xv.z, wi.z, gi); gi = fmaf(xv.w, wi.w, gi);
    gg = fmaf(xv.x, wg.x, gg); gg = fmaf(xv.y, wg.y, gg);
    gg = fmaf(xv.z, wg.z, gg); gg = fmaf(xv.w, wg.w, gg);
    go = fmaf(xv.x, wo.x, go); go = fmaf(xv.y, wo.y, go);
    go = fmaf(xv.z, wo.z, go); go = fmaf(xv.w, wo.w, go);
    float ea = EXP2(gi), eb = EXP2(gg);
    float c = (1.0f - eb) * rcpf((1.0f + ea) * (1.0f + eb));
    float ec = EXP2(go), ed = EXP2(S2 * c);
    float h = (1.0f - ed) * rcpf((1.0f + ec) * (1.0f + ed));
    o0 = fmaf(h, wr.x, o0); o1 = fmaf(h, wr.y, o1);
    o2 = fmaf(h, wr.z, o2); o3 = fmaf(h, wr.w, o3);
  }

  ((float4*)pp)[(size_t)jsp * TSTEPS + t] = make_float4(o0, o1, o2, o3);
}

extern "C" void kernel_launch(void* const* d_in, const int* in_sizes, int n_in,
                              void* d_out, int out_size, void* d_ws, size_t ws_size,
                              hipStream_t stream) {
  const float* x    = (const float*)d_in[0];
  const float* Wih0 = (const float*)d_in[1];
  const float* bih0 = (const float*)d_in[3];
  const float* bhh0 = (const float*)d_in[4];
  const float* Whr0 = (const float*)d_in[5];
  const float* Wih1 = (const float*)d_in[6];
  const float* bih1 = (const float*)d_in[8];
  const float* bhh1 = (const float*)d_in[9];
  const float* Whr1 = (const float*)d_in[10];
  const float* Wih2 = (const float*)d_in[11];
  const float* bih2 = (const float*)d_in[13];
  const float* bhh2 = (const float*)d_in[14];
  const float* Whr2 = (const float*)d_in[15];
  float* out = (float*)d_out;
  float* ws = (float*)d_ws;
  float* pp = ws + WS_PP;

  prep_kernel<<<dim3(1360), dim3(256), 0, stream>>>(
      x, Wih0, bih0, bhh0, Wih1, bih1, bhh1, Whr1, Wih2, bih2, bhh2, Whr2, ws);

  lstm_layer0_mfma<<<dim3(2048), dim3(256), 0, stream>>>(
      (const u16*)(ws + WS_XHI), (const u16*)(ws + WS_XLO),
      (const u16*)(ws + WS_WHI), (const u16*)(ws + WS_WLO),
      ws + WS_BSC, Whr0, pp);
  reduce64<<<dim3(128), dim3(256), 0, stream>>>(pp, ws + WS_Y0);

  lstm_small<<<dim3(2048), dim3(256), 0, stream>>>(ws + WS_Y0, ws + WS_C1, pp);
  reduce64<<<dim3(128), dim3(256), 0, stream>>>(pp, ws + WS_Y1);

  lstm_small<<<dim3(2048), dim3(256), 0, stream>>>(ws + WS_Y1, ws + WS_C2, pp);
  reduce64<<<dim3(128), dim3(256), 0, stream>>>(pp, out);
}